// Round 1
// baseline (786.996 us; speedup 1.0000x reference)
//
#include <hip/hip_runtime.h>

#define SS 32
#define TT 512
#define FF 512
#define NSTEP 12
#define NNEG 32
#define NC 33

typedef __attribute__((ext_vector_type(8))) short short8;
typedef __attribute__((ext_vector_type(4))) float floatx4;

__device__ __forceinline__ unsigned f2bf1(float x){
  union { float f; unsigned u; } v; v.f = x;
  return (v.u + 0x7FFFu + ((v.u >> 16) & 1u)) >> 16;   // RNE
}

// true_latent fp32 -> bf16 (packed), 4 elems/thread
__global__ void k_convert_tl(const float* __restrict__ tl, unsigned short* __restrict__ out){
  int idx = blockIdx.x * 256 + threadIdx.x;
  float4 v = ((const float4*)tl)[idx];
  uint2 r;
  r.x = f2bf1(v.x) | (f2bf1(v.y) << 16);
  r.y = f2bf1(v.z) | (f2bf1(v.w) << 16);
  ((uint2*)out)[idx] = r;
}

// predictions[s][t][f][i] fp32 -> predT[s][i][t][f] bf16.
// One block per (s,t): 6144 floats in (coalesced float4), LDS transpose (pad 13), bf16x2 out (coalesced).
__global__ void k_transpose_pred(const float* __restrict__ pred, unsigned short* __restrict__ predT){
  __shared__ float lds[FF * 13];
  const float4* in4 = (const float4*)(pred + (size_t)blockIdx.x * (FF * NSTEP));
  #pragma unroll
  for (int it = 0; it < 6; ++it){
    int idx = it * 256 + threadIdx.x;      // 0..1535
    float4 v = in4[idx];
    int j = idx * 4;
    float vv[4] = {v.x, v.y, v.z, v.w};
    #pragma unroll
    for (int e = 0; e < 4; ++e){
      int jj = j + e;
      int f = jj / NSTEP;
      int i = jj - f * NSTEP;
      lds[f * 13 + i] = vv[e];
    }
  }
  __syncthreads();
  int sb = blockIdx.x >> 9;
  int tb = blockIdx.x & 511;
  int f0 = threadIdx.x * 2;
  #pragma unroll
  for (int i = 0; i < NSTEP; ++i){
    unsigned val = f2bf1(lds[f0 * 13 + i]) | (f2bf1(lds[(f0 + 1) * 13 + i]) << 16);
    ((unsigned*)predT)[ ((sb * NSTEP + i) * TT + tb) * (FF / 2) + threadIdx.x ] = val;
  }
}

// One block per (s,u). 33 gathered target rows -> LDS (B), 12 contiguous predT rows -> LDS (A),
// 3 waves x [16 n x 16 kb] mfma_f32_16x16x32_bf16, logsumexp per i-row, one atomicAdd.
__global__ __launch_bounds__(256) void k_main(const unsigned short* __restrict__ predT,
                                              const unsigned short* __restrict__ tlb,
                                              const int* __restrict__ nidx,
                                              float* __restrict__ out){
  __shared__ unsigned short Bl[48 * 520];   // rows 33..47 garbage, outputs discarded
  __shared__ unsigned short Al[16 * 520];   // rows 12..15 garbage
  __shared__ float outl[16 * 49];
  __shared__ float lossl[16];
  __shared__ int rows[NC];

  int b = blockIdx.x;
  int s = b >> 9, u = b & 511;
  int tid = threadIdx.x;

  if (tid < NC){
    int r = u;                               // c==0: positive at time u
    if (tid > 0){
      int j = (tid - 1) * TT + u;            // flat index into neg_indices, reshape is (neg, T)
      int ni = nidx[s * (NNEG * TT) + j];
      r = ni + (ni >= (j >> 5) ? 1 : 0);     // t_rep[j] = j // NEG, skip-t adjust
    }
    rows[tid] = r;
  }
  __syncthreads();

  // B: 33 rows x 1KB, uint4 loads (L2-resident tlb)
  for (int k = tid; k < NC * 64; k += 256){
    int c = k >> 6, p = k & 63;
    const uint4* src = (const uint4*)(tlb + ((size_t)(s * TT + rows[c]) << 9));
    *(uint4*)(&Bl[c * 520 + p * 8]) = src[p];
  }
  // A: rows i -> predT[s][i][u-i][:], contiguous, each read exactly once device-wide
  for (int k = tid; k < NSTEP * 64; k += 256){
    int i = k >> 6, p = k & 63;
    int t = u - i;
    if (t >= 0){
      const uint4* src = (const uint4*)(predT + ((size_t)((s * NSTEP + i) * TT + t) << 9));
      *(uint4*)(&Al[i * 520 + p * 8]) = src[p];
    }
  }
  __syncthreads();

  int wave = tid >> 6, lane = tid & 63;
  if (wave < 3){
    int mn = lane & 15, kg = lane >> 4;
    floatx4 acc = {0.f, 0.f, 0.f, 0.f};
    #pragma unroll
    for (int kb = 0; kb < 16; ++kb){
      short8 a  = *(const short8*)(&Al[mn * 520 + kb * 32 + kg * 8]);
      short8 bb = *(const short8*)(&Bl[(wave * 16 + mn) * 520 + kb * 32 + kg * 8]);
      acc = __builtin_amdgcn_mfma_f32_16x16x32_bf16(a, bb, acc, 0, 0, 0);
    }
    int c0 = wave * 16 + mn;                  // col = lane&15 (n), row = (lane>>4)*4 + reg (m)
    if (c0 < NC){
      #pragma unroll
      for (int r = 0; r < 4; ++r){
        int m = kg * 4 + r;
        outl[m * 49 + c0] = acc[r];
      }
    }
  }
  __syncthreads();

  int imax = u < NSTEP - 1 ? u : NSTEP - 1;   // valid i: t = u-i >= 0
  if (tid <= imax){
    const float* row = &outl[tid * 49];
    float mx = row[0];
    for (int c = 1; c < NC; ++c) mx = fmaxf(mx, row[c]);
    float sum = 0.f;
    for (int c = 0; c < NC; ++c) sum += __expf(row[c] - mx);
    lossl[tid] = mx + __logf(sum) - row[0];
  }
  __syncthreads();
  if (tid == 0){
    float tot = 0.f;
    for (int i = 0; i <= imax; ++i) tot += lossl[i];
    atomicAdd(out, tot);
  }
}

extern "C" void kernel_launch(void* const* d_in, const int* in_sizes, int n_in,
                              void* d_out, int out_size, void* d_ws, size_t ws_size,
                              hipStream_t stream){
  const float* tl   = (const float*)d_in[0];
  const float* pred = (const float*)d_in[1];
  const int*   ni   = (const int*)d_in[2];

  unsigned short* predT = (unsigned short*)d_ws;                       // 32*12*512*512 bf16 = 201 MB
  unsigned short* tlb   = predT + (size_t)SS * NSTEP * TT * FF;        // 32*512*512 bf16 = 16.8 MB

  hipMemsetAsync(d_out, 0, sizeof(float) * out_size, stream);
  k_convert_tl<<<8192, 256, 0, stream>>>(tl, tlb);
  k_transpose_pred<<<SS * TT, 256, 0, stream>>>(pred, predT);
  k_main<<<SS * TT, 256, 0, stream>>>(predT, tlb, ni, (float*)d_out);
}

// Round 2
// 776.309 us; speedup vs baseline: 1.0138x; 1.0138x over previous
//
#include <hip/hip_runtime.h>

#define SS 32
#define TT 512
#define FF 512
#define NSTEP 12
#define NNEG 32
#define NC 33

typedef __attribute__((ext_vector_type(8))) short short8;
typedef __attribute__((ext_vector_type(4))) float floatx4;

__device__ __forceinline__ unsigned f2bf1(float x){
  union { float f; unsigned u; } v; v.f = x;
  return (v.u + 0x7FFFu + ((v.u >> 16) & 1u)) >> 16;   // RNE
}

// true_latent fp32 -> bf16 (packed), 4 elems/thread
__global__ void k_convert_tl(const float* __restrict__ tl, unsigned short* __restrict__ out){
  int idx = blockIdx.x * 256 + threadIdx.x;
  float4 v = ((const float4*)tl)[idx];
  uint2 r;
  r.x = f2bf1(v.x) | (f2bf1(v.y) << 16);
  r.y = f2bf1(v.z) | (f2bf1(v.w) << 16);
  ((uint2*)out)[idx] = r;
}

// predictions[s][t][f][i] fp32 -> predT[s][i][t][f] bf16.
// One block per (s,t): 6144 floats in (coalesced float4), LDS transpose (pad 13), bf16x2 out (coalesced).
__global__ void k_transpose_pred(const float* __restrict__ pred, unsigned short* __restrict__ predT){
  __shared__ float lds[FF * 13];
  const float4* in4 = (const float4*)(pred + (size_t)blockIdx.x * (FF * NSTEP));
  #pragma unroll
  for (int it = 0; it < 6; ++it){
    int idx = it * 256 + threadIdx.x;      // 0..1535
    float4 v = in4[idx];
    int j = idx * 4;
    float vv[4] = {v.x, v.y, v.z, v.w};
    #pragma unroll
    for (int e = 0; e < 4; ++e){
      int jj = j + e;
      int f = jj / NSTEP;
      int i = jj - f * NSTEP;
      lds[f * 13 + i] = vv[e];
    }
  }
  __syncthreads();
  int sb = blockIdx.x >> 9;
  int tb = blockIdx.x & 511;
  int f0 = threadIdx.x * 2;
  #pragma unroll
  for (int i = 0; i < NSTEP; ++i){
    unsigned val = f2bf1(lds[f0 * 13 + i]) | (f2bf1(lds[(f0 + 1) * 13 + i]) << 16);
    ((unsigned*)predT)[ ((sb * NSTEP + i) * TT + tb) * (FF / 2) + threadIdx.x ] = val;
  }
}

// One block per (s,u). 33 gathered target rows -> LDS (B), 12 contiguous predT rows -> LDS (A),
// 3 waves x [16 n x 16 kb] mfma_f32_16x16x32_bf16, logsumexp per i-row, one plain store.
__global__ __launch_bounds__(256) void k_main(const unsigned short* __restrict__ predT,
                                              const unsigned short* __restrict__ tlb,
                                              const int* __restrict__ nidx,
                                              float* __restrict__ part){
  __shared__ unsigned short Bl[48 * 520];   // rows 33..47 garbage, outputs discarded
  __shared__ unsigned short Al[16 * 520];   // rows 12..15 garbage
  __shared__ float outl[16 * 49];
  __shared__ float lossl[16];
  __shared__ int rows[NC];

  int b = blockIdx.x;
  int s = b >> 9, u = b & 511;
  int tid = threadIdx.x;

  if (tid < NC){
    int r = u;                               // c==0: positive at time u
    if (tid > 0){
      int j = (tid - 1) * TT + u;            // flat index into neg_indices, reshape is (neg, T)
      int ni = nidx[s * (NNEG * TT) + j];
      r = ni + (ni >= (j >> 5) ? 1 : 0);     // t_rep[j] = j // NEG, skip-t adjust
    }
    rows[tid] = r;
  }
  __syncthreads();

  // B: 33 rows x 1KB, uint4 loads (L2-resident tlb)
  for (int k = tid; k < NC * 64; k += 256){
    int c = k >> 6, p = k & 63;
    const uint4* src = (const uint4*)(tlb + ((size_t)(s * TT + rows[c]) << 9));
    *(uint4*)(&Bl[c * 520 + p * 8]) = src[p];
  }
  // A: rows i -> predT[s][i][u-i][:], contiguous, each read exactly once device-wide
  for (int k = tid; k < NSTEP * 64; k += 256){
    int i = k >> 6, p = k & 63;
    int t = u - i;
    if (t >= 0){
      const uint4* src = (const uint4*)(predT + ((size_t)((s * NSTEP + i) * TT + t) << 9));
      *(uint4*)(&Al[i * 520 + p * 8]) = src[p];
    }
  }
  __syncthreads();

  int wave = tid >> 6, lane = tid & 63;
  if (wave < 3){
    int mn = lane & 15, kg = lane >> 4;
    floatx4 acc = {0.f, 0.f, 0.f, 0.f};
    #pragma unroll
    for (int kb = 0; kb < 16; ++kb){
      short8 a  = *(const short8*)(&Al[mn * 520 + kb * 32 + kg * 8]);
      short8 bb = *(const short8*)(&Bl[(wave * 16 + mn) * 520 + kb * 32 + kg * 8]);
      acc = __builtin_amdgcn_mfma_f32_16x16x32_bf16(a, bb, acc, 0, 0, 0);
    }
    int c0 = wave * 16 + mn;                  // col = lane&15 (n), row = (lane>>4)*4 + reg (m)
    if (c0 < NC){
      #pragma unroll
      for (int r = 0; r < 4; ++r){
        int m = kg * 4 + r;
        outl[m * 49 + c0] = acc[r];
      }
    }
  }
  __syncthreads();

  int imax = u < NSTEP - 1 ? u : NSTEP - 1;   // valid i: t = u-i >= 0
  if (tid <= imax){
    const float* row = &outl[tid * 49];
    float mx = row[0];
    for (int c = 1; c < NC; ++c) mx = fmaxf(mx, row[c]);
    float sum = 0.f;
    for (int c = 0; c < NC; ++c) sum += __expf(row[c] - mx);
    lossl[tid] = mx + __logf(sum) - row[0];
  }
  __syncthreads();
  if (tid == 0){
    float tot = 0.f;
    for (int i = 0; i <= imax; ++i) tot += lossl[i];
    part[b] = tot;                            // plain store; no same-address atomic storm
  }
}

// Single-block final reduction over 16384 partials -> d_out[0]
__global__ __launch_bounds__(256) void k_reduce(const float* __restrict__ part, float* __restrict__ out){
  float s = 0.f;
  for (int i = threadIdx.x; i < SS * TT; i += 256) s += part[i];
  #pragma unroll
  for (int off = 32; off > 0; off >>= 1) s += __shfl_down(s, off, 64);
  __shared__ float w[4];
  if ((threadIdx.x & 63) == 0) w[threadIdx.x >> 6] = s;
  __syncthreads();
  if (threadIdx.x == 0) out[0] = w[0] + w[1] + w[2] + w[3];
}

extern "C" void kernel_launch(void* const* d_in, const int* in_sizes, int n_in,
                              void* d_out, int out_size, void* d_ws, size_t ws_size,
                              hipStream_t stream){
  const float* tl   = (const float*)d_in[0];
  const float* pred = (const float*)d_in[1];
  const int*   ni   = (const int*)d_in[2];

  unsigned short* predT = (unsigned short*)d_ws;                       // 32*12*512*512 bf16 = 201 MB
  unsigned short* tlb   = predT + (size_t)SS * NSTEP * TT * FF;        // 32*512*512 bf16 = 16.8 MB
  float*          partp = (float*)(tlb + (size_t)SS * TT * FF);        // 16384 floats

  k_convert_tl<<<8192, 256, 0, stream>>>(tl, tlb);
  k_transpose_pred<<<SS * TT, 256, 0, stream>>>(pred, predT);
  k_main<<<SS * TT, 256, 0, stream>>>(predT, tlb, ni, partp);
  k_reduce<<<1, 256, 0, stream>>>(partp, (float*)d_out);
}

// Round 3
// 629.162 us; speedup vs baseline: 1.2509x; 1.2339x over previous
//
#include <hip/hip_runtime.h>

#define SS 32
#define TT 512
#define FF 512
#define NSTEP 12
#define NNEG 32
#define NC 33

typedef __attribute__((ext_vector_type(4))) float floatx4;

__device__ __forceinline__ unsigned pk4_fp8(float a, float b, float c, float d){
  unsigned r = __builtin_amdgcn_cvt_pk_fp8_f32(a, b, 0, false);
  r = __builtin_amdgcn_cvt_pk_fp8_f32(c, d, r, true);
  return r;
}

// true_latent fp32 -> fp8 e4m3, 4 elems/thread
__global__ void k_convert_tl(const float* __restrict__ tl, unsigned char* __restrict__ out){
  int idx = blockIdx.x * 256 + threadIdx.x;
  float4 v = ((const float4*)tl)[idx];
  ((unsigned*)out)[idx] = pk4_fp8(v.x, v.y, v.z, v.w);
}

// predictions[s][t][f][i] fp32 -> predT8[s][i][t][f] fp8.
// One block per (s,t): 6144 floats in (coalesced float4), LDS transpose (pad 13), fp8x4 out (coalesced).
__global__ void k_transpose_pred(const float* __restrict__ pred, unsigned char* __restrict__ predT8){
  __shared__ float lds[FF * 13];
  const float4* in4 = (const float4*)(pred + (size_t)blockIdx.x * (FF * NSTEP));
  #pragma unroll
  for (int it = 0; it < 6; ++it){
    int idx = it * 256 + threadIdx.x;      // 0..1535
    float4 v = in4[idx];
    int j = idx * 4;
    float vv[4] = {v.x, v.y, v.z, v.w};
    #pragma unroll
    for (int e = 0; e < 4; ++e){
      int jj = j + e;
      int f = jj / NSTEP;
      int i = jj - f * NSTEP;
      lds[f * 13 + i] = vv[e];
    }
  }
  __syncthreads();
  int sb = blockIdx.x >> 9;
  int tb = blockIdx.x & 511;
  int half = threadIdx.x >> 7;             // 0..1 (two i-rows in flight)
  int fq = threadIdx.x & 127;              // f-quad index
  int fo = fq * 4;
  #pragma unroll
  for (int ip = 0; ip < 6; ++ip){
    int i = ip * 2 + half;
    unsigned r = pk4_fp8(lds[fo * 13 + i], lds[(fo + 1) * 13 + i],
                         lds[(fo + 2) * 13 + i], lds[(fo + 3) * 13 + i]);
    ((unsigned*)predT8)[ ((sb * NSTEP + i) * TT + tb) * 128 + fq ] = r;
  }
}

// One block per (s,u). 33 gathered fp8 target rows -> LDS (B), 12 contiguous predT8 rows -> LDS (A),
// 3 waves x [16 n x 16 kb] mfma_f32_16x16x32_fp8_fp8, logsumexp per i-row, plain partial store.
#define PITCH 544   // bytes per LDS row (16-aligned); chunks XOR-swizzled to dodge bank conflicts
__global__ __launch_bounds__(256) void k_main(const unsigned char* __restrict__ predT8,
                                              const unsigned char* __restrict__ tlb8,
                                              const int* __restrict__ nidx,
                                              float* __restrict__ part){
  __shared__ unsigned char Bl[48 * PITCH];   // rows 33..47 garbage, outputs discarded
  __shared__ unsigned char Al[16 * PITCH];   // rows 12..15 garbage
  __shared__ float outl[16 * 49];
  __shared__ float lossl[16];
  __shared__ int rows[NC];

  int b = blockIdx.x;
  int s = b >> 9, u = b & 511;
  int tid = threadIdx.x;

  if (tid < NC){
    int r = u;                               // c==0: positive at time u
    if (tid > 0){
      int j = (tid - 1) * TT + u;            // flat index into neg_indices, reshape is (neg, T)
      int ni = nidx[s * (NNEG * TT) + j];
      r = ni + (ni >= (j >> 5) ? 1 : 0);     // t_rep[j] = j // NEG, skip-t adjust
    }
    rows[tid] = r;
  }
  __syncthreads();

  // B: 33 rows x 512B, uint4 loads (L2-resident tlb8), XOR-swizzled LDS placement
  for (int k = tid; k < NC * 32; k += 256){
    int c = k >> 5, p = k & 31;
    const uint4* src = (const uint4*)(tlb8 + ((size_t)(s * TT + rows[c]) << 9));
    *(uint4*)(&Bl[c * PITCH + ((p ^ (c & 31)) << 4)]) = src[p];
  }
  // A: rows i -> predT8[s][i][u-i][:], contiguous, each read exactly once device-wide
  for (int k = tid; k < NSTEP * 32; k += 256){
    int i = k >> 5, p = k & 31;
    int t = u - i;
    if (t >= 0){
      const uint4* src = (const uint4*)(predT8 + ((size_t)((s * NSTEP + i) * TT + t) << 9));
      *(uint4*)(&Al[i * PITCH + ((p ^ i) << 4)]) = src[p];
    }
  }
  __syncthreads();

  int wave = tid >> 6, lane = tid & 63;
  if (wave < 3){
    int mn = lane & 15, kg = lane >> 4;
    int kh = kg >> 1, kl = kg & 1;          // 16B chunk half-select
    int br = wave * 16 + mn;
    floatx4 acc = {0.f, 0.f, 0.f, 0.f};
    #pragma unroll
    for (int kb = 0; kb < 16; ++kb){
      int pc = kb * 2 + kh;
      long a  = *(const long*)(&Al[mn * PITCH + ((pc ^ mn) << 4) + kl * 8]);
      long bb = *(const long*)(&Bl[br * PITCH + ((pc ^ (br & 31)) << 4) + kl * 8]);
      acc = __builtin_amdgcn_mfma_f32_16x16x32_fp8_fp8(a, bb, acc, 0, 0, 0);
    }
    if (br < NC){
      #pragma unroll
      for (int r = 0; r < 4; ++r){
        int m = kg * 4 + r;                 // col = lane&15 (n), row = (lane>>4)*4 + reg (m)
        outl[m * 49 + br] = acc[r];
      }
    }
  }
  __syncthreads();

  int imax = u < NSTEP - 1 ? u : NSTEP - 1;   // valid i: t = u-i >= 0
  if (tid <= imax){
    const float* row = &outl[tid * 49];
    float mx = row[0];
    for (int c = 1; c < NC; ++c) mx = fmaxf(mx, row[c]);
    float sum = 0.f;
    for (int c = 0; c < NC; ++c) sum += __expf(row[c] - mx);
    lossl[tid] = mx + __logf(sum) - row[0];
  }
  __syncthreads();
  if (tid == 0){
    float tot = 0.f;
    for (int i = 0; i <= imax; ++i) tot += lossl[i];
    part[b] = tot;
  }
}

// Single-block final reduction over 16384 partials -> d_out[0]
__global__ __launch_bounds__(256) void k_reduce(const float* __restrict__ part, float* __restrict__ out){
  float s = 0.f;
  for (int i = threadIdx.x; i < SS * TT; i += 256) s += part[i];
  #pragma unroll
  for (int off = 32; off > 0; off >>= 1) s += __shfl_down(s, off, 64);
  __shared__ float w[4];
  if ((threadIdx.x & 63) == 0) w[threadIdx.x >> 6] = s;
  __syncthreads();
  if (threadIdx.x == 0) out[0] = w[0] + w[1] + w[2] + w[3];
}

extern "C" void kernel_launch(void* const* d_in, const int* in_sizes, int n_in,
                              void* d_out, int out_size, void* d_ws, size_t ws_size,
                              hipStream_t stream){
  const float* tl   = (const float*)d_in[0];
  const float* pred = (const float*)d_in[1];
  const int*   ni   = (const int*)d_in[2];

  unsigned char* predT8 = (unsigned char*)d_ws;                        // 32*12*512*512 fp8 = 100.7 MB
  unsigned char* tlb8   = predT8 + (size_t)SS * NSTEP * TT * FF;       // 32*512*512 fp8 = 8.4 MB
  float*         partp  = (float*)(tlb8 + (size_t)SS * TT * FF);       // 16384 floats

  k_convert_tl<<<SS * TT * FF / 1024, 256, 0, stream>>>(tl, tlb8);
  k_transpose_pred<<<SS * TT, 256, 0, stream>>>(pred, predT8);
  k_main<<<SS * TT, 256, 0, stream>>>(predT8, tlb8, ni, partp);
  k_reduce<<<1, 256, 0, stream>>>(partp, (float*)d_out);
}